// Round 1
// baseline (58.911 us; speedup 1.0000x reference)
//
#include <hip/hip_runtime.h>
#include <math.h>

#define OFFSET_C 1e-6f
#define EPS_C 1e-6f

// Single-block kernel: 4096 pairs, each thread handles m/1024 rows,
// wave shuffle-reduce (64-lane) then cross-wave LDS reduce.
__global__ __launch_bounds__(1024) void iou3d_loss_kernel(
    const float* __restrict__ pred, const float* __restrict__ target,
    float* __restrict__ out, int m)
{
    int tid = threadIdx.x;
    float loss_sum = 0.f;
    float npos = 0.f;

    for (int i = tid; i < m; i += blockDim.x) {
        const float* p = pred + i * 7;
        const float* t = target + i * 7;
        float px = p[0], py = p[1], pz = p[2], pw = p[3], pl = p[4], ph = p[5], pa = p[6];
        float tx = t[0], ty = t[1], tz = t[2], tw = t[3], tl = t[4], th = t[5], ta = t[6];

        // BEV standup extents of the rotated rectangle (exact: equals corner min/max)
        float pc = cosf(pa), ps = sinf(pa);
        float tc = cosf(ta), ts = sinf(ta);
        float pex = 0.5f * (fabsf(pw * pc) + fabsf(pl * ps));
        float pey = 0.5f * (fabsf(pw * ps) + fabsf(pl * pc));
        float tex = 0.5f * (fabsf(tw * tc) + fabsf(tl * ts));
        float tey = 0.5f * (fabsf(tw * ts) + fabsf(tl * tc));

        // axis-aligned overlap (with reference's +offset inside the clamp)
        float ltx = fmaxf(px - pex, tx - tex);
        float lty = fmaxf(py - pey, ty - tey);
        float rbx = fminf(px + pex, tx + tex);
        float rby = fminf(py + pey, ty + tey);
        float wx = fmaxf(rbx - ltx + OFFSET_C, 0.f);
        float wy = fmaxf(rby - lty + OFFSET_C, 0.f);
        float overlap_bev = wx * wy;

        // height overlap: z is box top
        float oh = fmaxf(fminf(pz, tz) - fmaxf(pz - ph, tz - th), 0.f);
        float o3 = overlap_bev * oh;

        float pvol = pw * pl * ph;
        float tvol = tw * tl * th;
        float denom = fmaxf(pvol + tvol - o3, EPS_C);
        float iou = o3 / denom;
        iou = fminf(fmaxf(iou, EPS_C), 1.0f);

        bool valid = (pw > 0.f) && (pl > 0.f) && (ph > 0.f);
        if (valid) {
            loss_sum += -logf(iou);
            npos += 1.f;
        }
    }

    // 64-lane wave reduction
    #pragma unroll
    for (int off = 32; off > 0; off >>= 1) {
        loss_sum += __shfl_down(loss_sum, off, 64);
        npos     += __shfl_down(npos, off, 64);
    }

    __shared__ float s_sum[16];
    __shared__ float s_n[16];
    int wave = tid >> 6;
    int lane = tid & 63;
    if (lane == 0) { s_sum[wave] = loss_sum; s_n[wave] = npos; }
    __syncthreads();

    if (tid == 0) {
        float S = 0.f, N = 0.f;
        int nw = (int)(blockDim.x >> 6);
        for (int w = 0; w < nw; ++w) { S += s_sum[w]; N += s_n[w]; }
        out[0] = (N > 0.f) ? (S / fmaxf(N, 1.f)) : 0.f;
    }
}

extern "C" void kernel_launch(void* const* d_in, const int* in_sizes, int n_in,
                              void* d_out, int out_size, void* d_ws, size_t ws_size,
                              hipStream_t stream) {
    const float* pred   = (const float*)d_in[0];
    const float* target = (const float*)d_in[1];
    float* out = (float*)d_out;
    int m = in_sizes[0] / 7;

    iou3d_loss_kernel<<<1, 1024, 0, stream>>>(pred, target, out, m);
}

// Round 3
// 56.402 us; speedup vs baseline: 1.0445x; 1.0445x over previous
//
#include <hip/hip_runtime.h>
#include <math.h>

#define OFFSET_C 1e-6f
#define EPS_C 1e-6f

// One pair per thread, 16 blocks x 256 threads.
// Each block WRITES its partial (sum, count) to ws[2*bid..2*bid+1] —
// overwrites harness poison, so no memset dispatch needed.
__global__ __launch_bounds__(256) void iou3d_pair_kernel(
    const float* __restrict__ pred, const float* __restrict__ target,
    float* __restrict__ ws, int m)
{
    int i = blockIdx.x * blockDim.x + threadIdx.x;
    float loss = 0.f, npos = 0.f;

    if (i < m) {
        const float* p = pred + i * 7;
        const float* t = target + i * 7;
        float px = p[0], py = p[1], pz = p[2], pw = p[3], pl = p[4], ph = p[5], pa = p[6];
        float tx = t[0], ty = t[1], tz = t[2], tw = t[3], tl = t[4], th = t[5], ta = t[6];

        // BEV standup half-extents of the rotated rect (exact corner min/max)
        float pc = __cosf(pa), ps = __sinf(pa);
        float tc = __cosf(ta), ts = __sinf(ta);
        float pex = 0.5f * (fabsf(pw * pc) + fabsf(pl * ps));
        float pey = 0.5f * (fabsf(pw * ps) + fabsf(pl * pc));
        float tex = 0.5f * (fabsf(tw * tc) + fabsf(tl * ts));
        float tey = 0.5f * (fabsf(tw * ts) + fabsf(tl * tc));

        float ltx = fmaxf(px - pex, tx - tex);
        float lty = fmaxf(py - pey, ty - tey);
        float rbx = fminf(px + pex, tx + tex);
        float rby = fminf(py + pey, ty + tey);
        float wx = fmaxf(rbx - ltx + OFFSET_C, 0.f);
        float wy = fmaxf(rby - lty + OFFSET_C, 0.f);
        float overlap_bev = wx * wy;

        // height overlap: z is box top
        float oh = fmaxf(fminf(pz, tz) - fmaxf(pz - ph, tz - th), 0.f);
        float o3 = overlap_bev * oh;

        float pvol = pw * pl * ph;
        float tvol = tw * tl * th;
        float denom = fmaxf(pvol + tvol - o3, EPS_C);
        float iou = fminf(fmaxf(o3 / denom, EPS_C), 1.0f);

        bool valid = (pw > 0.f) && (pl > 0.f) && (ph > 0.f);
        if (valid) {
            loss = -__logf(iou);
            npos = 1.f;
        }
    }

    // 64-lane wave reduction
    #pragma unroll
    for (int off = 32; off > 0; off >>= 1) {
        loss += __shfl_down(loss, off, 64);
        npos += __shfl_down(npos, off, 64);
    }

    __shared__ float s_sum[4];
    __shared__ float s_n[4];
    int wave = threadIdx.x >> 6;
    int lane = threadIdx.x & 63;
    if (lane == 0) { s_sum[wave] = loss; s_n[wave] = npos; }
    __syncthreads();

    if (threadIdx.x == 0) {
        ws[2 * blockIdx.x]     = s_sum[0] + s_sum[1] + s_sum[2] + s_sum[3];
        ws[2 * blockIdx.x + 1] = s_n[0] + s_n[1] + s_n[2] + s_n[3];
    }
}

// Single wave: reduce nblocks partial pairs, write scalar loss.
__global__ __launch_bounds__(64) void iou3d_finalize_kernel(
    const float* __restrict__ ws, float* __restrict__ out, int nblocks)
{
    int lane = threadIdx.x;
    float S = (lane < nblocks) ? ws[2 * lane]     : 0.f;
    float N = (lane < nblocks) ? ws[2 * lane + 1] : 0.f;
    #pragma unroll
    for (int off = 32; off > 0; off >>= 1) {
        S += __shfl_down(S, off, 64);
        N += __shfl_down(N, off, 64);
    }
    if (lane == 0)
        out[0] = (N > 0.f) ? (S / fmaxf(N, 1.f)) : 0.f;
}

extern "C" void kernel_launch(void* const* d_in, const int* in_sizes, int n_in,
                              void* d_out, int out_size, void* d_ws, size_t ws_size,
                              hipStream_t stream) {
    const float* pred   = (const float*)d_in[0];
    const float* target = (const float*)d_in[1];
    float* out = (float*)d_out;
    float* ws  = (float*)d_ws;
    int m = in_sizes[0] / 7;

    int block = 256;
    int grid = (m + block - 1) / block;   // 16 blocks for m=4096
    iou3d_pair_kernel<<<grid, block, 0, stream>>>(pred, target, ws, m);
    iou3d_finalize_kernel<<<1, 64, 0, stream>>>(ws, out, grid);
}